// Round 9
// baseline (298.118 us; speedup 1.0000x reference)
//
#include <hip/hip_runtime.h>
#include <cstddef>

#define D_MODEL 1024
#define NH 16
#define HD 64
#define BATCH 4
#define SEQ 2048
#define MTOT (BATCH * SEQ)  // 8192

typedef _Float16 half8 __attribute__((ext_vector_type(8)));
typedef _Float16 half4v __attribute__((ext_vector_type(4)));
typedef float f32x4 __attribute__((ext_vector_type(4)));

#if __has_builtin(__builtin_amdgcn_exp2f)
#define EXP2(x) __builtin_amdgcn_exp2f(x)
#else
#define EXP2(x) __expf((x)*0.69314718056f)
#endif

// async global->LDS, 16B per lane. LDS dest must be wave-uniform base (+lane*16 implicit).
#define ASYNC_COPY16(g, l)                                                    \
    __builtin_amdgcn_global_load_lds(                                         \
        (__attribute__((address_space(1))) const void*)(g),                   \
        (__attribute__((address_space(3))) void*)(l), 16, 0, 0)

// Swizzled LDS access: logical element (R, CH f16-cols) of a [*][64] f16 tile
// lives at byte R*128 + ((CH*2) ^ ((R&7)<<4)).  Producer (glds with inverse-swz
// global source, or ds_write at the swizzled offset) pairs with this read:
// conflict-free (proven 0-conflict in the GEMM).
#define LDSFRAG(S, R, CH)                                                     \
    (*(const half8*)((const char*)(S) + ((R) << 7) +                          \
                     ((((CH) << 1)) ^ (((R) & 7) << 4))))
// matching swizzled-write address (byte pointer) for row R, f16-col CH
#define LDSWADDR(S, R, CH)                                                    \
    ((half8*)((char*)(S) + ((R) << 7) + ((((CH) << 1)) ^ (((R) & 7) << 4))))

// ---------------------------------------------------------------------------
// Fused prep (unchanged):
//   blocks 0..255    : x fp32 -> f16 (4096 half8 chunks per block)
//   blocks 256..1279 : 4 weight matrices fp32 [k][n] -> f16 transposed [n][k]
// ---------------------------------------------------------------------------
__global__ __launch_bounds__(256) void prep(
    const float* __restrict__ x, _Float16* __restrict__ xh,
    const float* __restrict__ W0, const float* __restrict__ W1,
    const float* __restrict__ W2, const float* __restrict__ W3,
    _Float16* __restrict__ T0, _Float16* __restrict__ T1,
    _Float16* __restrict__ T2, _Float16* __restrict__ T3)
{
    __shared__ float T[64][65];
    const int bid = blockIdx.x;
    if (bid < 256) {
        const size_t base = (size_t)bid * 4096 + threadIdx.x;
#pragma unroll
        for (int it = 0; it < 16; ++it) {
            const size_t i = base + (size_t)it * 256;
            const float4* p = (const float4*)x + 2 * i;
            float4 a = p[0], b = p[1];
            half8 h;
            h[0] = (_Float16)a.x; h[1] = (_Float16)a.y; h[2] = (_Float16)a.z; h[3] = (_Float16)a.w;
            h[4] = (_Float16)b.x; h[5] = (_Float16)b.y; h[6] = (_Float16)b.z; h[7] = (_Float16)b.w;
            *((half8*)xh + i) = h;
        }
    } else {
        const int t = bid - 256;
        const int mtx = t >> 8;
        const float* W = (mtx == 0) ? W0 : (mtx == 1) ? W1 : (mtx == 2) ? W2 : W3;
        _Float16*   Wt = (mtx == 0) ? T0 : (mtx == 1) ? T1 : (mtx == 2) ? T2 : T3;
        const int tile = t & 255;
        const int k0 = (tile >> 4) * 64, n0 = (tile & 15) * 64;
        const int r = threadIdx.x >> 4, c4 = (threadIdx.x & 15) * 4;

#pragma unroll
        for (int i = 0; i < 4; ++i) {
            float4 v = *(const float4*)(W + (size_t)(k0 + r + 16 * i) * 1024 + n0 + c4);
            T[r + 16 * i][c4 + 0] = v.x; T[r + 16 * i][c4 + 1] = v.y;
            T[r + 16 * i][c4 + 2] = v.z; T[r + 16 * i][c4 + 3] = v.w;
        }
        __syncthreads();
#pragma unroll
        for (int i = 0; i < 4; ++i) {
            const int n = r + 16 * i;
            half4v h;
            h[0] = (_Float16)T[c4 + 0][n]; h[1] = (_Float16)T[c4 + 1][n];
            h[2] = (_Float16)T[c4 + 2][n]; h[3] = (_Float16)T[c4 + 3][n];
            *(half4v*)(Wt + (size_t)(n0 + n) * 1024 + k0 + c4) = h;
        }
    }
}

// ---------------------------------------------------------------------------
// MFMA f16 GEMM — EXACT round-1 version (proven 80.5 us QKV / 0 conflicts).
// ---------------------------------------------------------------------------
template <int QKV>
__global__ __launch_bounds__(256) void gemm_mfma(
    const _Float16* __restrict__ A,
    const _Float16* __restrict__ Bt0, const _Float16* __restrict__ Bt1, const _Float16* __restrict__ Bt2,
    const float* __restrict__ bi0, const float* __restrict__ bi1, const float* __restrict__ bi2,
    void* __restrict__ C0, void* __restrict__ C1, void* __restrict__ C2)
{
    const int L = blockIdx.x;
    const int y = L & 63;
    const int c_ = L >> 6;
    const int z  = QKV ? (c_ >> 3) : 0;
    const int xb = QKV ? (c_ & 7) : c_;

    const _Float16* Bt = (z == 0) ? Bt0 : (z == 1) ? Bt1 : Bt2;
    const float*   bia = (z == 0) ? bi0 : (z == 1) ? bi1 : bi2;
    void*            C = (z == 0) ? C0  : (z == 1) ? C1  : C2;

    __shared__ _Float16 As[128][64];
    __shared__ _Float16 Bs[128][64];

    const int tid  = threadIdx.x;
    const int w    = tid >> 6;
    const int lane = tid & 63;
    const int l15  = lane & 15;
    const int lg   = lane >> 4;
    const int m0 = y * 128;
    const int n0 = xb * 128;
    const int wm = (w >> 1) * 64, wn = (w & 1) * 64;

    const int rsub = lane >> 3;                       // 0..7
    const int cswz = ((lane & 7) ^ rsub) * 8;         // halves

    const _Float16* gA = A  + (size_t)(m0 + 32 * w + rsub) * 1024 + cswz;
    const _Float16* gB = Bt + (size_t)(n0 + 32 * w + rsub) * 1024 + cswz;
    char* lA = (char*)As + (size_t)(w * 4) * 1024;
    char* lB = (char*)Bs + (size_t)(w * 4) * 1024;

    f32x4 acc[4][4];
#pragma unroll
    for (int i = 0; i < 4; ++i)
#pragma unroll
        for (int j = 0; j < 4; ++j) { acc[i][j][0] = 0.f; acc[i][j][1] = 0.f; acc[i][j][2] = 0.f; acc[i][j][3] = 0.f; }

    for (int kt = 0; kt < 16; ++kt) {
        const int k0 = kt * 64;
        __syncthreads();  // all reads of previous tile done before overwrite
#pragma unroll
        for (int i = 0; i < 4; ++i) {
            ASYNC_COPY16(gA + (size_t)(8 * i) * 1024 + k0, lA + i * 1024);
            ASYNC_COPY16(gB + (size_t)(8 * i) * 1024 + k0, lB + i * 1024);
        }
        __syncthreads();  // compiler drains vmcnt(0) before s_barrier -> tile visible

#pragma unroll
        for (int c = 0; c < 2; ++c) {
            half8 af[4], bf[4];
#pragma unroll
            for (int i = 0; i < 4; ++i) af[i] = LDSFRAG(As, wm + 16 * i + l15, 32 * c + 8 * lg);
#pragma unroll
            for (int j = 0; j < 4; ++j) bf[j] = LDSFRAG(Bs, wn + 16 * j + l15, 32 * c + 8 * lg);
#pragma unroll
            for (int i = 0; i < 4; ++i)
#pragma unroll
                for (int j = 0; j < 4; ++j)
                    acc[i][j] = __builtin_amdgcn_mfma_f32_16x16x32_f16(af[i], bf[j], acc[i][j], 0, 0, 0);
        }
    }

    float bvv[4];
#pragma unroll
    for (int j = 0; j < 4; ++j) bvv[j] = bia[n0 + wn + 16 * j + l15];

#pragma unroll
    for (int i = 0; i < 4; ++i)
#pragma unroll
        for (int j = 0; j < 4; ++j)
#pragma unroll
            for (int r = 0; r < 4; ++r) {
                const int m = m0 + wm + 16 * i + 4 * lg + r;
                const int n = n0 + wn + 16 * j + l15;
                const float val = acc[i][j][r] + bvv[j];
                if (QKV) {
                    const int bb = m >> 11, ss = m & 2047, hh = n >> 6, hd = n & 63;
                    if (z < 2)   // Q, K: [bh][s][hd]
                        ((_Float16*)C)[((size_t)(bb * NH + hh) * SEQ + ss) * HD + hd] = (_Float16)val;
                    else         // V: transposed [bh][d][s]
                        ((_Float16*)C)[((size_t)(bb * NH + hh) * HD + hd) * SEQ + ss] = (_Float16)val;
                } else {
                    ((float*)C)[(size_t)m * 1024 + n] = val;
                }
            }
}

// ---------------------------------------------------------------------------
// Causal flash attention v9 = v8 + dual Q-fragment (q-tile 128/block).
// Round-8 diagnosis: LDS instruction pipe ~75% busy (24 wave-instrs/tile x
// 12cy x 4 waves x 132 tiles/CU = 152K of 201K cy) — every wave read the
// FULL K/V tile to serve only 16 q-rows.  Fix: each wave owns 32 q-rows
// (2 fragments u=0,1); each kb/vb LDS fragment feeds 2 MFMAs.  Per-q LDS
// drops 1.5 -> 0.94 instr; block-tiles 33792 -> 17408 (64bh x 8qtb x 34).
// All v8 machinery kept: swapped QK^T (packed half4 Ps), XOR-swizzled K/V,
// bh->XCD affinity (bid = qtb*64 + bh, 512 blocks, bid%8 = bh%8).
// Diagonal now spans k-tiles 2qt & 2qt+1: mask when kt >= 2*qt with global
// compare  kt*64+16f+4lg+r  >  q0+16(2w+u)+l15.
// Pairing stays exact: pass0 (32-2qtb) + pass1 (2qtb+2) = 34 tiles/block.
// LDS 34.8 KB -> 4 blocks/CU.
// ---------------------------------------------------------------------------
__global__ __launch_bounds__(256, 4) void attn_fwd_mfma(
    const _Float16* __restrict__ Q, const _Float16* __restrict__ K,
    const _Float16* __restrict__ Vt, _Float16* __restrict__ O)
{
    __shared__ _Float16 Ks[64][64];
    __shared__ _Float16 Vs[64][64];
    __shared__ _Float16 Ps[8][16][72];   // [q-group 2w+u][q=l15][k], pitch 144B

    const int tid  = threadIdx.x;
    const int w    = tid >> 6;
    const int lane = tid & 63;
    const int l15  = lane & 15;
    const int lg   = lane >> 4;

    const int bid = blockIdx.x;
    const int bh  = bid & 63;          // bid%8 == bh%8 -> XCD affinity
    const int qtb = bid >> 6;          // 0..7
    const int b  = bh >> 4, h = bh & 15;

    const _Float16* Qb  = Q  + (size_t)bh * SEQ * HD;
    const _Float16* Kb  = K  + (size_t)bh * SEQ * HD;   // [s][d]
    const _Float16* Vtb = Vt + (size_t)bh * HD * SEQ;   // [d][s]

    const int srow = tid >> 3;         // 0..31
    const int scol = (tid & 7) * 8;    // f16 cols

    for (int pass = 0; pass < 2; ++pass) {
        const int qt = pass ? qtb : (15 - qtb);
        const int q0 = qt * 128;
        const int ntiles = 2 * qt + 2;

        // ---- Q: two fragments per wave (rows 16*(2w+u)+l15 of the q-tile) ----
        half8 qa[2][2];
#pragma unroll
        for (int u = 0; u < 2; ++u) {
            const _Float16* qp = Qb + (size_t)(q0 + 16 * (2 * w + u) + l15) * HD + 8 * lg;
            qa[u][0] = *(const half8*)(qp);
            qa[u][1] = *(const half8*)(qp + 32);
#pragma unroll
            for (int c = 0; c < 2; ++c)
#pragma unroll
                for (int j = 0; j < 8; ++j)
                    qa[u][c][j] = (_Float16)((float)qa[u][c][j] * 0.18033688f);
        }

        f32x4 o_[2][4];
#pragma unroll
        for (int u = 0; u < 2; ++u)
#pragma unroll
            for (int ft = 0; ft < 4; ++ft) { o_[u][ft][0] = 0.f; o_[u][ft][1] = 0.f; o_[u][ft][2] = 0.f; o_[u][ft][3] = 0.f; }
        float lp_t[2] = {0.f, 0.f};

        half8 kreg[2], vreg[2];
#pragma unroll
        for (int j = 0; j < 2; ++j) {
            kreg[j] = *(const half8*)(Kb  + (size_t)(srow + 32 * j) * HD + scol);
            vreg[j] = *(const half8*)(Vtb + (size_t)(srow + 32 * j) * SEQ + scol);
        }

        for (int kt = 0; kt < ntiles; ++kt) {
            __syncthreads();
#pragma unroll
            for (int j = 0; j < 2; ++j) {
                const int row = srow + 32 * j;
                *LDSWADDR(Ks, row, scol) = kreg[j];
                *LDSWADDR(Vs, row, scol) = vreg[j];
            }
            __syncthreads();

            if (kt + 1 < ntiles) {
                const int k0 = (kt + 1) * 64;
#pragma unroll
                for (int j = 0; j < 2; ++j) {
                    kreg[j] = *(const half8*)(Kb  + (size_t)(k0 + srow + 32 * j) * HD + scol);
                    vreg[j] = *(const half8*)(Vtb + (size_t)(srow + 32 * j) * SEQ + k0 + scol);
                }
            }

            // ---- S^T = K Q^T : 16 MFMAs on 8 kb reads (2 q-frags share kb) ----
            f32x4 s0[4], s1[4];
#pragma unroll
            for (int f = 0; f < 4; ++f) {
                s0[f][0] = 0.f; s0[f][1] = 0.f; s0[f][2] = 0.f; s0[f][3] = 0.f;
                s1[f][0] = 0.f; s1[f][1] = 0.f; s1[f][2] = 0.f; s1[f][3] = 0.f;
            }
#pragma unroll
            for (int c = 0; c < 2; ++c)
#pragma unroll
                for (int f = 0; f < 4; ++f) {
                    half8 kb = LDSFRAG(Ks, 16 * f + l15, 32 * c + 8 * lg);
                    s0[f] = __builtin_amdgcn_mfma_f32_16x16x32_f16(kb, qa[0][c], s0[f], 0, 0, 0);
                    s1[f] = __builtin_amdgcn_mfma_f32_16x16x32_f16(kb, qa[1][c], s1[f], 0, 0, 0);
                }

            // ---- p = exp2(s), mask (diag spans last 2 tiles), packed stash ----
            const bool dg = (kt >= 2 * qt);
#pragma unroll
            for (int u = 0; u < 2; ++u) {
                const int qg = q0 + 16 * (2 * w + u) + l15;   // global q row
#pragma unroll
                for (int f = 0; f < 4; ++f) {
                    half4v ph;
#pragma unroll
                    for (int r = 0; r < 4; ++r) {
                        const float sv = (u == 0) ? s0[f][r] : s1[f][r];
                        float p = EXP2(sv);
                        if (dg && (kt * 64 + 16 * f + 4 * lg + r > qg)) p = 0.f;
                        lp_t[u] += p;
                        ph[r] = (_Float16)p;
                    }
                    *(half4v*)&Ps[2 * w + u][l15][16 * f + 4 * lg] = ph;
                }
            }

            // ---- O += P V : 16 MFMAs on 8 vb reads ----
            half8 pa0[2], pa1[2];
            pa0[0] = *(const half8*)&Ps[2 * w][l15][8 * lg];
            pa0[1] = *(const half8*)&Ps[2 * w][l15][32 + 8 * lg];
            pa1[0] = *(const half8*)&Ps[2 * w + 1][l15][8 * lg];
            pa1[1] = *(const half8*)&Ps[2 * w + 1][l15][32 + 8 * lg];
#pragma unroll
            for (int c = 0; c < 2; ++c)
#pragma unroll
                for (int ft = 0; ft < 4; ++ft) {
                    half8 vb = LDSFRAG(Vs, 16 * ft + l15, 32 * c + 8 * lg);
                    o_[0][ft] = __builtin_amdgcn_mfma_f32_16x16x32_f16(pa0[c], vb, o_[0][ft], 0, 0, 0);
                    o_[1][ft] = __builtin_amdgcn_mfma_f32_16x16x32_f16(pa1[c], vb, o_[1][ft], 0, 0, 0);
                }
        }

        // ---- epilogue per fragment: rowsum at q=l15; O rows q=4lg+r ----
#pragma unroll
        for (int u = 0; u < 2; ++u) {
            float rs = lp_t[u];
            rs += __shfl_xor(rs, 16);
            rs += __shfl_xor(rs, 32);
            // lanes 0..15 now hold rowsum(q = lane index) for this fragment
#pragma unroll
            for (int r = 0; r < 4; ++r) {
                const float inv = 1.0f / __shfl(rs, 4 * lg + r, 64);
                _Float16* orow = O + (size_t)(b * SEQ + q0 + 16 * (2 * w + u) + 4 * lg + r) * D_MODEL + h * HD + l15;
#pragma unroll
                for (int ft = 0; ft < 4; ++ft) orow[16 * ft] = (_Float16)(o_[u][ft][r] * inv);
            }
        }
        __syncthreads();  // Ps/Ks/Vs reuse across passes
    }
}

// ---------------------------------------------------------------------------
extern "C" void kernel_launch(void* const* d_in, const int* in_sizes, int n_in,
                              void* d_out, int out_size, void* d_ws, size_t ws_size,
                              hipStream_t stream)
{
    const float* x  = (const float*)d_in[0];
    const float* wq = (const float*)d_in[1];
    const float* bq = (const float*)d_in[2];
    const float* wk = (const float*)d_in[3];
    const float* bk = (const float*)d_in[4];
    const float* wv = (const float*)d_in[5];
    const float* bv = (const float*)d_in[6];
    const float* wo = (const float*)d_in[7];
    const float* bo = (const float*)d_in[8];
    float* out = (float*)d_out;

    const size_t SZ = (size_t)MTOT * D_MODEL;  // 8388608
    const size_t WZ = (size_t)D_MODEL * D_MODEL;

    _Float16* xh  = (_Float16*)d_ws;
    _Float16* wtq = xh + SZ;
    _Float16* wtk = wtq + WZ;
    _Float16* wtv = wtk + WZ;
    _Float16* wto = wtv + WZ;
    _Float16* Qh  = wto + WZ;
    _Float16* Kh  = Qh + SZ;
    _Float16* Vtg = Kh + SZ;   // V, already transposed [bh][d][s]
    _Float16* AOh = Vtg + SZ;  // total ~88 MiB

    // fused prep: x cvt (blocks 0..255) + 4 weight transposes (256..1279)
    prep<<<dim3(1280), 256, 0, stream>>>(x, xh, wq, wk, wv, wo, wtq, wtk, wtv, wto);
    // QKV projection: XCD-affinity 1D grid (1536 blocks), glds staging
    gemm_mfma<1><<<dim3(1536), 256, 0, stream>>>(xh, wtq, wtk, wtv, bq, bk, bv, Qh, Kh, Vtg);
    // attention: 1D grid, bid = qtb*64 + bh -> bh-XCD affinity; q-tile 128
    attn_fwd_mfma<<<dim3(512), 256, 0, stream>>>(Qh, Kh, Vtg, AOh);
    // output projection: XCD-affinity 1D grid (512 blocks)
    gemm_mfma<0><<<dim3(512), 256, 0, stream>>>(AOh, wto, wto, wto, bo, bo, bo, out, out, out);
}

// Round 10
// 263.325 us; speedup vs baseline: 1.1321x; 1.1321x over previous
//
#include <hip/hip_runtime.h>
#include <cstddef>

#define D_MODEL 1024
#define NH 16
#define HD 64
#define BATCH 4
#define SEQ 2048
#define MTOT (BATCH * SEQ)  // 8192

typedef _Float16 half8 __attribute__((ext_vector_type(8)));
typedef _Float16 half4v __attribute__((ext_vector_type(4)));
typedef float f32x4 __attribute__((ext_vector_type(4)));

#if __has_builtin(__builtin_amdgcn_exp2f)
#define EXP2(x) __builtin_amdgcn_exp2f(x)
#else
#define EXP2(x) __expf((x)*0.69314718056f)
#endif

// async global->LDS, 16B per lane. LDS dest must be wave-uniform base (+lane*16 implicit).
#define ASYNC_COPY16(g, l)                                                    \
    __builtin_amdgcn_global_load_lds(                                         \
        (__attribute__((address_space(1))) const void*)(g),                   \
        (__attribute__((address_space(3))) void*)(l), 16, 0, 0)

// Swizzled LDS access: logical element (R, CH f16-cols) of a [*][64] f16 tile
// lives at byte R*128 + ((CH*2) ^ ((R&7)<<4)).  Producer (glds with inverse-swz
// global source, or ds_write at the swizzled offset) pairs with this read:
// conflict-free (proven 0-conflict in the GEMM).
#define LDSFRAG(S, R, CH)                                                     \
    (*(const half8*)((const char*)(S) + ((R) << 7) +                          \
                     ((((CH) << 1)) ^ (((R) & 7) << 4))))
// matching swizzled-write address (byte pointer) for row R, f16-col CH
#define LDSWADDR(S, R, CH)                                                    \
    ((half8*)((char*)(S) + ((R) << 7) + ((((CH) << 1)) ^ (((R) & 7) << 4))))

// ---------------------------------------------------------------------------
// Fused prep (unchanged):
//   blocks 0..255    : x fp32 -> f16 (4096 half8 chunks per block)
//   blocks 256..1279 : 4 weight matrices fp32 [k][n] -> f16 transposed [n][k]
// ---------------------------------------------------------------------------
__global__ __launch_bounds__(256) void prep(
    const float* __restrict__ x, _Float16* __restrict__ xh,
    const float* __restrict__ W0, const float* __restrict__ W1,
    const float* __restrict__ W2, const float* __restrict__ W3,
    _Float16* __restrict__ T0, _Float16* __restrict__ T1,
    _Float16* __restrict__ T2, _Float16* __restrict__ T3)
{
    __shared__ float T[64][65];
    const int bid = blockIdx.x;
    if (bid < 256) {
        const size_t base = (size_t)bid * 4096 + threadIdx.x;
#pragma unroll
        for (int it = 0; it < 16; ++it) {
            const size_t i = base + (size_t)it * 256;
            const float4* p = (const float4*)x + 2 * i;
            float4 a = p[0], b = p[1];
            half8 h;
            h[0] = (_Float16)a.x; h[1] = (_Float16)a.y; h[2] = (_Float16)a.z; h[3] = (_Float16)a.w;
            h[4] = (_Float16)b.x; h[5] = (_Float16)b.y; h[6] = (_Float16)b.z; h[7] = (_Float16)b.w;
            *((half8*)xh + i) = h;
        }
    } else {
        const int t = bid - 256;
        const int mtx = t >> 8;
        const float* W = (mtx == 0) ? W0 : (mtx == 1) ? W1 : (mtx == 2) ? W2 : W3;
        _Float16*   Wt = (mtx == 0) ? T0 : (mtx == 1) ? T1 : (mtx == 2) ? T2 : T3;
        const int tile = t & 255;
        const int k0 = (tile >> 4) * 64, n0 = (tile & 15) * 64;
        const int r = threadIdx.x >> 4, c4 = (threadIdx.x & 15) * 4;

#pragma unroll
        for (int i = 0; i < 4; ++i) {
            float4 v = *(const float4*)(W + (size_t)(k0 + r + 16 * i) * 1024 + n0 + c4);
            T[r + 16 * i][c4 + 0] = v.x; T[r + 16 * i][c4 + 1] = v.y;
            T[r + 16 * i][c4 + 2] = v.z; T[r + 16 * i][c4 + 3] = v.w;
        }
        __syncthreads();
#pragma unroll
        for (int i = 0; i < 4; ++i) {
            const int n = r + 16 * i;
            half4v h;
            h[0] = (_Float16)T[c4 + 0][n]; h[1] = (_Float16)T[c4 + 1][n];
            h[2] = (_Float16)T[c4 + 2][n]; h[3] = (_Float16)T[c4 + 3][n];
            *(half4v*)(Wt + (size_t)(n0 + n) * 1024 + k0 + c4) = h;
        }
    }
}

// ---------------------------------------------------------------------------
// MFMA f16 GEMM — EXACT round-1 version (proven 80.5 us QKV / 0 conflicts).
// ---------------------------------------------------------------------------
template <int QKV>
__global__ __launch_bounds__(256) void gemm_mfma(
    const _Float16* __restrict__ A,
    const _Float16* __restrict__ Bt0, const _Float16* __restrict__ Bt1, const _Float16* __restrict__ Bt2,
    const float* __restrict__ bi0, const float* __restrict__ bi1, const float* __restrict__ bi2,
    void* __restrict__ C0, void* __restrict__ C1, void* __restrict__ C2)
{
    const int L = blockIdx.x;
    const int y = L & 63;
    const int c_ = L >> 6;
    const int z  = QKV ? (c_ >> 3) : 0;
    const int xb = QKV ? (c_ & 7) : c_;

    const _Float16* Bt = (z == 0) ? Bt0 : (z == 1) ? Bt1 : Bt2;
    const float*   bia = (z == 0) ? bi0 : (z == 1) ? bi1 : bi2;
    void*            C = (z == 0) ? C0  : (z == 1) ? C1  : C2;

    __shared__ _Float16 As[128][64];
    __shared__ _Float16 Bs[128][64];

    const int tid  = threadIdx.x;
    const int w    = tid >> 6;
    const int lane = tid & 63;
    const int l15  = lane & 15;
    const int lg   = lane >> 4;
    const int m0 = y * 128;
    const int n0 = xb * 128;
    const int wm = (w >> 1) * 64, wn = (w & 1) * 64;

    const int rsub = lane >> 3;                       // 0..7
    const int cswz = ((lane & 7) ^ rsub) * 8;         // halves

    const _Float16* gA = A  + (size_t)(m0 + 32 * w + rsub) * 1024 + cswz;
    const _Float16* gB = Bt + (size_t)(n0 + 32 * w + rsub) * 1024 + cswz;
    char* lA = (char*)As + (size_t)(w * 4) * 1024;
    char* lB = (char*)Bs + (size_t)(w * 4) * 1024;

    f32x4 acc[4][4];
#pragma unroll
    for (int i = 0; i < 4; ++i)
#pragma unroll
        for (int j = 0; j < 4; ++j) { acc[i][j][0] = 0.f; acc[i][j][1] = 0.f; acc[i][j][2] = 0.f; acc[i][j][3] = 0.f; }

    for (int kt = 0; kt < 16; ++kt) {
        const int k0 = kt * 64;
        __syncthreads();  // all reads of previous tile done before overwrite
#pragma unroll
        for (int i = 0; i < 4; ++i) {
            ASYNC_COPY16(gA + (size_t)(8 * i) * 1024 + k0, lA + i * 1024);
            ASYNC_COPY16(gB + (size_t)(8 * i) * 1024 + k0, lB + i * 1024);
        }
        __syncthreads();  // compiler drains vmcnt(0) before s_barrier -> tile visible

#pragma unroll
        for (int c = 0; c < 2; ++c) {
            half8 af[4], bf[4];
#pragma unroll
            for (int i = 0; i < 4; ++i) af[i] = LDSFRAG(As, wm + 16 * i + l15, 32 * c + 8 * lg);
#pragma unroll
            for (int j = 0; j < 4; ++j) bf[j] = LDSFRAG(Bs, wn + 16 * j + l15, 32 * c + 8 * lg);
#pragma unroll
            for (int i = 0; i < 4; ++i)
#pragma unroll
                for (int j = 0; j < 4; ++j)
                    acc[i][j] = __builtin_amdgcn_mfma_f32_16x16x32_f16(af[i], bf[j], acc[i][j], 0, 0, 0);
        }
    }

    float bvv[4];
#pragma unroll
    for (int j = 0; j < 4; ++j) bvv[j] = bia[n0 + wn + 16 * j + l15];

#pragma unroll
    for (int i = 0; i < 4; ++i)
#pragma unroll
        for (int j = 0; j < 4; ++j)
#pragma unroll
            for (int r = 0; r < 4; ++r) {
                const int m = m0 + wm + 16 * i + 4 * lg + r;
                const int n = n0 + wn + 16 * j + l15;
                const float val = acc[i][j][r] + bvv[j];
                if (QKV) {
                    const int bb = m >> 11, ss = m & 2047, hh = n >> 6, hd = n & 63;
                    if (z < 2)   // Q, K: [bh][s][hd]
                        ((_Float16*)C)[((size_t)(bb * NH + hh) * SEQ + ss) * HD + hd] = (_Float16)val;
                    else         // V: transposed [bh][d][s]
                        ((_Float16*)C)[((size_t)(bb * NH + hh) * HD + hd) * SEQ + ss] = (_Float16)val;
                } else {
                    ((float*)C)[(size_t)m * 1024 + n] = val;
                }
            }
}

// ---------------------------------------------------------------------------
// Causal flash attention v10 = v9's dual-Q amortization at v8's occupancy.
// Round-9 lesson: pairing halved the grid to 512 = 2 blocks/CU (grid-limited;
// Occupancy 21%) and lost more to exposed latency than the LDS reduction
// gained.  v10: one 128-row q-tile per block -> 16 qt x 64 bh = 1024 blocks;
// ALL co-resident (4 x 34.8 KB = 139 KB/CU, VGPR 64).  Balance comes from
// longest-first dispatch (qt = 15 - bid>>6: 32-tile blocks launch first);
// each CU's 4 slots then span the qt spectrum -> per-CU work ~68 tile-units
// uniformly.  bh = bid&63 keeps XCD affinity (64%8==0).
// Everything else = v9: swapped QK^T packed-half4 Ps, XOR-swizzled K/V,
// dual Q-fragment (kb/vb each feed 2 MFMAs), diag mask kt>=2qt with
// global compare, per-fragment rowsum via shfl.
// ---------------------------------------------------------------------------
__global__ __launch_bounds__(256, 4) void attn_fwd_mfma(
    const _Float16* __restrict__ Q, const _Float16* __restrict__ K,
    const _Float16* __restrict__ Vt, _Float16* __restrict__ O)
{
    __shared__ _Float16 Ks[64][64];
    __shared__ _Float16 Vs[64][64];
    __shared__ _Float16 Ps[8][16][72];   // [q-group 2w+u][q=l15][k], pitch 144B

    const int tid  = threadIdx.x;
    const int w    = tid >> 6;
    const int lane = tid & 63;
    const int l15  = lane & 15;
    const int lg   = lane >> 4;

    const int bid = blockIdx.x;
    const int bh  = bid & 63;          // bid%8 == bh%8 -> XCD affinity
    const int qt  = 15 - (bid >> 6);   // longest blocks dispatch first
    const int b  = bh >> 4, h = bh & 15;

    const _Float16* Qb  = Q  + (size_t)bh * SEQ * HD;
    const _Float16* Kb  = K  + (size_t)bh * SEQ * HD;   // [s][d]
    const _Float16* Vtb = Vt + (size_t)bh * HD * SEQ;   // [d][s]

    const int srow = tid >> 3;         // 0..31
    const int scol = (tid & 7) * 8;    // f16 cols

    const int q0 = qt * 128;
    const int ntiles = 2 * qt + 2;

    // ---- Q: two fragments per wave (rows 16*(2w+u)+l15 of the q-tile) ----
    half8 qa[2][2];
#pragma unroll
    for (int u = 0; u < 2; ++u) {
        const _Float16* qp = Qb + (size_t)(q0 + 16 * (2 * w + u) + l15) * HD + 8 * lg;
        qa[u][0] = *(const half8*)(qp);
        qa[u][1] = *(const half8*)(qp + 32);
#pragma unroll
        for (int c = 0; c < 2; ++c)
#pragma unroll
            for (int j = 0; j < 8; ++j)
                qa[u][c][j] = (_Float16)((float)qa[u][c][j] * 0.18033688f);
    }

    f32x4 o_[2][4];
#pragma unroll
    for (int u = 0; u < 2; ++u)
#pragma unroll
        for (int ft = 0; ft < 4; ++ft) { o_[u][ft][0] = 0.f; o_[u][ft][1] = 0.f; o_[u][ft][2] = 0.f; o_[u][ft][3] = 0.f; }
    float lp_t[2] = {0.f, 0.f};

    half8 kreg[2], vreg[2];
#pragma unroll
    for (int j = 0; j < 2; ++j) {
        kreg[j] = *(const half8*)(Kb  + (size_t)(srow + 32 * j) * HD + scol);
        vreg[j] = *(const half8*)(Vtb + (size_t)(srow + 32 * j) * SEQ + scol);
    }

    for (int kt = 0; kt < ntiles; ++kt) {
        __syncthreads();
#pragma unroll
        for (int j = 0; j < 2; ++j) {
            const int row = srow + 32 * j;
            *LDSWADDR(Ks, row, scol) = kreg[j];
            *LDSWADDR(Vs, row, scol) = vreg[j];
        }
        __syncthreads();

        if (kt + 1 < ntiles) {
            const int k0 = (kt + 1) * 64;
#pragma unroll
            for (int j = 0; j < 2; ++j) {
                kreg[j] = *(const half8*)(Kb  + (size_t)(k0 + srow + 32 * j) * HD + scol);
                vreg[j] = *(const half8*)(Vtb + (size_t)(srow + 32 * j) * SEQ + k0 + scol);
            }
        }

        // ---- S^T = K Q^T : 16 MFMAs on 8 kb reads (2 q-frags share kb) ----
        f32x4 s0[4], s1[4];
#pragma unroll
        for (int f = 0; f < 4; ++f) {
            s0[f][0] = 0.f; s0[f][1] = 0.f; s0[f][2] = 0.f; s0[f][3] = 0.f;
            s1[f][0] = 0.f; s1[f][1] = 0.f; s1[f][2] = 0.f; s1[f][3] = 0.f;
        }
#pragma unroll
        for (int c = 0; c < 2; ++c)
#pragma unroll
            for (int f = 0; f < 4; ++f) {
                half8 kb = LDSFRAG(Ks, 16 * f + l15, 32 * c + 8 * lg);
                s0[f] = __builtin_amdgcn_mfma_f32_16x16x32_f16(kb, qa[0][c], s0[f], 0, 0, 0);
                s1[f] = __builtin_amdgcn_mfma_f32_16x16x32_f16(kb, qa[1][c], s1[f], 0, 0, 0);
            }

        // ---- p = exp2(s), mask (diag spans last 2 tiles), packed stash ----
        const bool dg = (kt >= 2 * qt);
#pragma unroll
        for (int u = 0; u < 2; ++u) {
            const int qg = q0 + 16 * (2 * w + u) + l15;   // global q row
#pragma unroll
            for (int f = 0; f < 4; ++f) {
                half4v ph;
#pragma unroll
                for (int r = 0; r < 4; ++r) {
                    const float sv = (u == 0) ? s0[f][r] : s1[f][r];
                    float p = EXP2(sv);
                    if (dg && (kt * 64 + 16 * f + 4 * lg + r > qg)) p = 0.f;
                    lp_t[u] += p;
                    ph[r] = (_Float16)p;
                }
                *(half4v*)&Ps[2 * w + u][l15][16 * f + 4 * lg] = ph;
            }
        }

        // ---- O += P V : 16 MFMAs on 8 vb reads ----
        half8 pa0[2], pa1[2];
        pa0[0] = *(const half8*)&Ps[2 * w][l15][8 * lg];
        pa0[1] = *(const half8*)&Ps[2 * w][l15][32 + 8 * lg];
        pa1[0] = *(const half8*)&Ps[2 * w + 1][l15][8 * lg];
        pa1[1] = *(const half8*)&Ps[2 * w + 1][l15][32 + 8 * lg];
#pragma unroll
        for (int c = 0; c < 2; ++c)
#pragma unroll
            for (int ft = 0; ft < 4; ++ft) {
                half8 vb = LDSFRAG(Vs, 16 * ft + l15, 32 * c + 8 * lg);
                o_[0][ft] = __builtin_amdgcn_mfma_f32_16x16x32_f16(pa0[c], vb, o_[0][ft], 0, 0, 0);
                o_[1][ft] = __builtin_amdgcn_mfma_f32_16x16x32_f16(pa1[c], vb, o_[1][ft], 0, 0, 0);
            }
    }

    // ---- epilogue per fragment: rowsum at q=l15; O rows q=4lg+r ----
#pragma unroll
    for (int u = 0; u < 2; ++u) {
        float rs = lp_t[u];
        rs += __shfl_xor(rs, 16);
        rs += __shfl_xor(rs, 32);
        // lanes 0..15 now hold rowsum(q = lane index) for this fragment
#pragma unroll
        for (int r = 0; r < 4; ++r) {
            const float inv = 1.0f / __shfl(rs, 4 * lg + r, 64);
            _Float16* orow = O + (size_t)(b * SEQ + q0 + 16 * (2 * w + u) + 4 * lg + r) * D_MODEL + h * HD + l15;
#pragma unroll
            for (int ft = 0; ft < 4; ++ft) orow[16 * ft] = (_Float16)(o_[u][ft][r] * inv);
        }
    }
}

// ---------------------------------------------------------------------------
extern "C" void kernel_launch(void* const* d_in, const int* in_sizes, int n_in,
                              void* d_out, int out_size, void* d_ws, size_t ws_size,
                              hipStream_t stream)
{
    const float* x  = (const float*)d_in[0];
    const float* wq = (const float*)d_in[1];
    const float* bq = (const float*)d_in[2];
    const float* wk = (const float*)d_in[3];
    const float* bk = (const float*)d_in[4];
    const float* wv = (const float*)d_in[5];
    const float* bv = (const float*)d_in[6];
    const float* wo = (const float*)d_in[7];
    const float* bo = (const float*)d_in[8];
    float* out = (float*)d_out;

    const size_t SZ = (size_t)MTOT * D_MODEL;  // 8388608
    const size_t WZ = (size_t)D_MODEL * D_MODEL;

    _Float16* xh  = (_Float16*)d_ws;
    _Float16* wtq = xh + SZ;
    _Float16* wtk = wtq + WZ;
    _Float16* wtv = wtk + WZ;
    _Float16* wto = wtv + WZ;
    _Float16* Qh  = wto + WZ;
    _Float16* Kh  = Qh + SZ;
    _Float16* Vtg = Kh + SZ;   // V, already transposed [bh][d][s]
    _Float16* AOh = Vtg + SZ;  // total ~88 MiB

    // fused prep: x cvt (blocks 0..255) + 4 weight transposes (256..1279)
    prep<<<dim3(1280), 256, 0, stream>>>(x, xh, wq, wk, wv, wo, wtq, wtk, wtv, wto);
    // QKV projection: XCD-affinity 1D grid (1536 blocks), glds staging
    gemm_mfma<1><<<dim3(1536), 256, 0, stream>>>(xh, wtq, wtk, wtv, bq, bk, bv, Qh, Kh, Vtg);
    // attention: 1024 blocks (16 qt x 64 bh), longest-first, bh-XCD affinity
    attn_fwd_mfma<<<dim3(1024), 256, 0, stream>>>(Qh, Kh, Vtg, AOh);
    // output projection: XCD-affinity 1D grid (512 blocks)
    gemm_mfma<0><<<dim3(512), 256, 0, stream>>>(AOh, wto, wto, wto, bo, bo, bo, out, out, out);
}

// Round 11
// 253.444 us; speedup vs baseline: 1.1763x; 1.0390x over previous
//
#include <hip/hip_runtime.h>
#include <cstddef>

#define D_MODEL 1024
#define NH 16
#define HD 64
#define BATCH 4
#define SEQ 2048
#define MTOT (BATCH * SEQ)  // 8192

typedef _Float16 half8 __attribute__((ext_vector_type(8)));
typedef _Float16 half4v __attribute__((ext_vector_type(4)));
typedef float f32x4 __attribute__((ext_vector_type(4)));

#if __has_builtin(__builtin_amdgcn_exp2f)
#define EXP2(x) __builtin_amdgcn_exp2f(x)
#else
#define EXP2(x) __expf((x)*0.69314718056f)
#endif

// async global->LDS, 16B per lane. LDS dest must be wave-uniform base (+lane*16 implicit).
#define ASYNC_COPY16(g, l)                                                    \
    __builtin_amdgcn_global_load_lds(                                         \
        (__attribute__((address_space(1))) const void*)(g),                   \
        (__attribute__((address_space(3))) void*)(l), 16, 0, 0)

// Swizzled LDS access: logical element (R, CH f16-cols) of a [*][64] f16 tile
// lives at byte R*128 + ((CH*2) ^ ((R&7)<<4)).  Producer (glds with inverse-swz
// global source, or ds_write at the swizzled offset) pairs with this read:
// conflict-free (proven 0-conflict in the GEMM).
#define LDSFRAG(S, R, CH)                                                     \
    (*(const half8*)((const char*)(S) + ((R) << 7) +                          \
                     ((((CH) << 1)) ^ (((R) & 7) << 4))))
// matching swizzled-write address (byte pointer) for row R, f16-col CH
#define LDSWADDR(S, R, CH)                                                    \
    ((half8*)((char*)(S) + ((R) << 7) + ((((CH) << 1)) ^ (((R) & 7) << 4))))

// ---------------------------------------------------------------------------
// Fused prep (unchanged):
//   blocks 0..255    : x fp32 -> f16 (4096 half8 chunks per block)
//   blocks 256..1279 : 4 weight matrices fp32 [k][n] -> f16 transposed [n][k]
// ---------------------------------------------------------------------------
__global__ __launch_bounds__(256) void prep(
    const float* __restrict__ x, _Float16* __restrict__ xh,
    const float* __restrict__ W0, const float* __restrict__ W1,
    const float* __restrict__ W2, const float* __restrict__ W3,
    _Float16* __restrict__ T0, _Float16* __restrict__ T1,
    _Float16* __restrict__ T2, _Float16* __restrict__ T3)
{
    __shared__ float T[64][65];
    const int bid = blockIdx.x;
    if (bid < 256) {
        const size_t base = (size_t)bid * 4096 + threadIdx.x;
#pragma unroll
        for (int it = 0; it < 16; ++it) {
            const size_t i = base + (size_t)it * 256;
            const float4* p = (const float4*)x + 2 * i;
            float4 a = p[0], b = p[1];
            half8 h;
            h[0] = (_Float16)a.x; h[1] = (_Float16)a.y; h[2] = (_Float16)a.z; h[3] = (_Float16)a.w;
            h[4] = (_Float16)b.x; h[5] = (_Float16)b.y; h[6] = (_Float16)b.z; h[7] = (_Float16)b.w;
            *((half8*)xh + i) = h;
        }
    } else {
        const int t = bid - 256;
        const int mtx = t >> 8;
        const float* W = (mtx == 0) ? W0 : (mtx == 1) ? W1 : (mtx == 2) ? W2 : W3;
        _Float16*   Wt = (mtx == 0) ? T0 : (mtx == 1) ? T1 : (mtx == 2) ? T2 : T3;
        const int tile = t & 255;
        const int k0 = (tile >> 4) * 64, n0 = (tile & 15) * 64;
        const int r = threadIdx.x >> 4, c4 = (threadIdx.x & 15) * 4;

#pragma unroll
        for (int i = 0; i < 4; ++i) {
            float4 v = *(const float4*)(W + (size_t)(k0 + r + 16 * i) * 1024 + n0 + c4);
            T[r + 16 * i][c4 + 0] = v.x; T[r + 16 * i][c4 + 1] = v.y;
            T[r + 16 * i][c4 + 2] = v.z; T[r + 16 * i][c4 + 3] = v.w;
        }
        __syncthreads();
#pragma unroll
        for (int i = 0; i < 4; ++i) {
            const int n = r + 16 * i;
            half4v h;
            h[0] = (_Float16)T[c4 + 0][n]; h[1] = (_Float16)T[c4 + 1][n];
            h[2] = (_Float16)T[c4 + 2][n]; h[3] = (_Float16)T[c4 + 3][n];
            *(half4v*)(Wt + (size_t)(n0 + n) * 1024 + k0 + c4) = h;
        }
    }
}

// ---------------------------------------------------------------------------
// MFMA f16 GEMM — round-1 structure (proven 80.5 us QKV / 0 conflicts).
// Round-11 addition: Q pre-scale (0.125*log2e) folded into the z==0 epilogue
// (QKV=1 only), so the attention kernel loads Q raw.
// ---------------------------------------------------------------------------
template <int QKV>
__global__ __launch_bounds__(256) void gemm_mfma(
    const _Float16* __restrict__ A,
    const _Float16* __restrict__ Bt0, const _Float16* __restrict__ Bt1, const _Float16* __restrict__ Bt2,
    const float* __restrict__ bi0, const float* __restrict__ bi1, const float* __restrict__ bi2,
    void* __restrict__ C0, void* __restrict__ C1, void* __restrict__ C2)
{
    const int L = blockIdx.x;
    const int y = L & 63;
    const int c_ = L >> 6;
    const int z  = QKV ? (c_ >> 3) : 0;
    const int xb = QKV ? (c_ & 7) : c_;

    const _Float16* Bt = (z == 0) ? Bt0 : (z == 1) ? Bt1 : Bt2;
    const float*   bia = (z == 0) ? bi0 : (z == 1) ? bi1 : bi2;
    void*            C = (z == 0) ? C0  : (z == 1) ? C1  : C2;

    __shared__ _Float16 As[128][64];
    __shared__ _Float16 Bs[128][64];

    const int tid  = threadIdx.x;
    const int w    = tid >> 6;
    const int lane = tid & 63;
    const int l15  = lane & 15;
    const int lg   = lane >> 4;
    const int m0 = y * 128;
    const int n0 = xb * 128;
    const int wm = (w >> 1) * 64, wn = (w & 1) * 64;

    const int rsub = lane >> 3;                       // 0..7
    const int cswz = ((lane & 7) ^ rsub) * 8;         // halves

    const _Float16* gA = A  + (size_t)(m0 + 32 * w + rsub) * 1024 + cswz;
    const _Float16* gB = Bt + (size_t)(n0 + 32 * w + rsub) * 1024 + cswz;
    char* lA = (char*)As + (size_t)(w * 4) * 1024;
    char* lB = (char*)Bs + (size_t)(w * 4) * 1024;

    f32x4 acc[4][4];
#pragma unroll
    for (int i = 0; i < 4; ++i)
#pragma unroll
        for (int j = 0; j < 4; ++j) { acc[i][j][0] = 0.f; acc[i][j][1] = 0.f; acc[i][j][2] = 0.f; acc[i][j][3] = 0.f; }

    for (int kt = 0; kt < 16; ++kt) {
        const int k0 = kt * 64;
        __syncthreads();  // all reads of previous tile done before overwrite
#pragma unroll
        for (int i = 0; i < 4; ++i) {
            ASYNC_COPY16(gA + (size_t)(8 * i) * 1024 + k0, lA + i * 1024);
            ASYNC_COPY16(gB + (size_t)(8 * i) * 1024 + k0, lB + i * 1024);
        }
        __syncthreads();  // compiler drains vmcnt(0) before s_barrier -> tile visible

#pragma unroll
        for (int c = 0; c < 2; ++c) {
            half8 af[4], bf[4];
#pragma unroll
            for (int i = 0; i < 4; ++i) af[i] = LDSFRAG(As, wm + 16 * i + l15, 32 * c + 8 * lg);
#pragma unroll
            for (int j = 0; j < 4; ++j) bf[j] = LDSFRAG(Bs, wn + 16 * j + l15, 32 * c + 8 * lg);
#pragma unroll
            for (int i = 0; i < 4; ++i)
#pragma unroll
                for (int j = 0; j < 4; ++j)
                    acc[i][j] = __builtin_amdgcn_mfma_f32_16x16x32_f16(af[i], bf[j], acc[i][j], 0, 0, 0);
        }
    }

    float bvv[4];
#pragma unroll
    for (int j = 0; j < 4; ++j) bvv[j] = bia[n0 + wn + 16 * j + l15];

#pragma unroll
    for (int i = 0; i < 4; ++i)
#pragma unroll
        for (int j = 0; j < 4; ++j)
#pragma unroll
            for (int r = 0; r < 4; ++r) {
                const int m = m0 + wm + 16 * i + 4 * lg + r;
                const int n = n0 + wn + 16 * j + l15;
                float val = acc[i][j][r] + bvv[j];
                if (QKV) {
                    if (z == 0) val *= 0.18033688f;   // fold Q pre-scale (0.125*log2e)
                    const int bb = m >> 11, ss = m & 2047, hh = n >> 6, hd = n & 63;
                    if (z < 2)   // Q, K: [bh][s][hd]
                        ((_Float16*)C)[((size_t)(bb * NH + hh) * SEQ + ss) * HD + hd] = (_Float16)val;
                    else         // V: transposed [bh][d][s]
                        ((_Float16*)C)[((size_t)(bb * NH + hh) * HD + hd) * SEQ + ss] = (_Float16)val;
                } else {
                    ((float*)C)[(size_t)m * 1024 + n] = val;
                }
            }
}

// ---------------------------------------------------------------------------
// Causal flash attention v11 = v10 + double-buffered Ks/Vs -> ONE barrier/tile.
// Single-barrier safety proof: per wave, order is write buf[kt&1] -> sync(kt)
// -> compute(kt) -> write buf[(kt+1)&1].  A write to buf[(kt+1)&1] can only
// race reads of the same buffer from tile kt-1; to pass sync(kt) every wave
// finished compute(kt-1), so the race is barrier-separated.  Write-visibility
// for tile kt is sync(kt) itself.  Ps needs no barrier (per-wave private).
// Stage-writes of fast waves now overlap slow waves' PV; barrier drains per
// block drop 68 -> 34.  LDS 50.8 KB -> 3 blocks/CU (from 4): accepted trade.
// Q pre-scale removed (folded into QKV GEMM epilogue).
// Everything else = v10: dual Q-fragment, swapped QK^T packed-half4 Ps,
// XOR-swizzled K/V, 1024 blocks longest-first, bh->XCD affinity.
// ---------------------------------------------------------------------------
__global__ __launch_bounds__(256, 3) void attn_fwd_mfma(
    const _Float16* __restrict__ Q, const _Float16* __restrict__ K,
    const _Float16* __restrict__ Vt, _Float16* __restrict__ O)
{
    __shared__ _Float16 Ks[2][64][64];
    __shared__ _Float16 Vs[2][64][64];
    __shared__ _Float16 Ps[8][16][72];   // [q-group 2w+u][q=l15][k], pitch 144B

    const int tid  = threadIdx.x;
    const int w    = tid >> 6;
    const int lane = tid & 63;
    const int l15  = lane & 15;
    const int lg   = lane >> 4;

    const int bid = blockIdx.x;
    const int bh  = bid & 63;          // bid%8 == bh%8 -> XCD affinity
    const int qt  = 15 - (bid >> 6);   // longest blocks dispatch first
    const int b  = bh >> 4, h = bh & 15;

    const _Float16* Qb  = Q  + (size_t)bh * SEQ * HD;
    const _Float16* Kb  = K  + (size_t)bh * SEQ * HD;   // [s][d]
    const _Float16* Vtb = Vt + (size_t)bh * HD * SEQ;   // [d][s]

    const int srow = tid >> 3;         // 0..31
    const int scol = (tid & 7) * 8;    // f16 cols

    const int q0 = qt * 128;
    const int ntiles = 2 * qt + 2;

    // ---- Q: two fragments per wave (pre-scaled by the QKV GEMM) ----
    half8 qa[2][2];
#pragma unroll
    for (int u = 0; u < 2; ++u) {
        const _Float16* qp = Qb + (size_t)(q0 + 16 * (2 * w + u) + l15) * HD + 8 * lg;
        qa[u][0] = *(const half8*)(qp);
        qa[u][1] = *(const half8*)(qp + 32);
    }

    f32x4 o_[2][4];
#pragma unroll
    for (int u = 0; u < 2; ++u)
#pragma unroll
        for (int ft = 0; ft < 4; ++ft) { o_[u][ft][0] = 0.f; o_[u][ft][1] = 0.f; o_[u][ft][2] = 0.f; o_[u][ft][3] = 0.f; }
    float lp_t[2] = {0.f, 0.f};

    half8 kreg[2], vreg[2];
#pragma unroll
    for (int j = 0; j < 2; ++j) {
        kreg[j] = *(const half8*)(Kb  + (size_t)(srow + 32 * j) * HD + scol);
        vreg[j] = *(const half8*)(Vtb + (size_t)(srow + 32 * j) * SEQ + scol);
    }

    for (int kt = 0; kt < ntiles; ++kt) {
        const int cur = kt & 1;
        // ---- stage K/V(kt) into buf[cur] (WAR vs kt-2 reads: separated by
        //      sync(kt-1)); then the single barrier makes it visible ----
#pragma unroll
        for (int j = 0; j < 2; ++j) {
            const int row = srow + 32 * j;
            *LDSWADDR(&Ks[cur][0][0], row, scol) = kreg[j];
            *LDSWADDR(&Vs[cur][0][0], row, scol) = vreg[j];
        }
        __syncthreads();

        // prefetch tile kt+1 into registers (in flight during compute)
        if (kt + 1 < ntiles) {
            const int k0 = (kt + 1) * 64;
#pragma unroll
            for (int j = 0; j < 2; ++j) {
                kreg[j] = *(const half8*)(Kb  + (size_t)(k0 + srow + 32 * j) * HD + scol);
                vreg[j] = *(const half8*)(Vtb + (size_t)(srow + 32 * j) * SEQ + k0 + scol);
            }
        }

        // ---- S^T = K Q^T : 16 MFMAs on 8 kb reads (2 q-frags share kb) ----
        f32x4 s0[4], s1[4];
#pragma unroll
        for (int f = 0; f < 4; ++f) {
            s0[f][0] = 0.f; s0[f][1] = 0.f; s0[f][2] = 0.f; s0[f][3] = 0.f;
            s1[f][0] = 0.f; s1[f][1] = 0.f; s1[f][2] = 0.f; s1[f][3] = 0.f;
        }
#pragma unroll
        for (int c = 0; c < 2; ++c)
#pragma unroll
            for (int f = 0; f < 4; ++f) {
                half8 kb = LDSFRAG(&Ks[cur][0][0], 16 * f + l15, 32 * c + 8 * lg);
                s0[f] = __builtin_amdgcn_mfma_f32_16x16x32_f16(kb, qa[0][c], s0[f], 0, 0, 0);
                s1[f] = __builtin_amdgcn_mfma_f32_16x16x32_f16(kb, qa[1][c], s1[f], 0, 0, 0);
            }

        // ---- p = exp2(s), mask (diag spans last 2 tiles), packed stash ----
        const bool dg = (kt >= 2 * qt);
#pragma unroll
        for (int u = 0; u < 2; ++u) {
            const int qg = q0 + 16 * (2 * w + u) + l15;   // global q row
#pragma unroll
            for (int f = 0; f < 4; ++f) {
                half4v ph;
#pragma unroll
                for (int r = 0; r < 4; ++r) {
                    const float sv = (u == 0) ? s0[f][r] : s1[f][r];
                    float p = EXP2(sv);
                    if (dg && (kt * 64 + 16 * f + 4 * lg + r > qg)) p = 0.f;
                    lp_t[u] += p;
                    ph[r] = (_Float16)p;
                }
                *(half4v*)&Ps[2 * w + u][l15][16 * f + 4 * lg] = ph;
            }
        }

        // ---- O += P V : 16 MFMAs on 8 vb reads ----
        half8 pa0[2], pa1[2];
        pa0[0] = *(const half8*)&Ps[2 * w][l15][8 * lg];
        pa0[1] = *(const half8*)&Ps[2 * w][l15][32 + 8 * lg];
        pa1[0] = *(const half8*)&Ps[2 * w + 1][l15][8 * lg];
        pa1[1] = *(const half8*)&Ps[2 * w + 1][l15][32 + 8 * lg];
#pragma unroll
        for (int c = 0; c < 2; ++c)
#pragma unroll
            for (int ft = 0; ft < 4; ++ft) {
                half8 vb = LDSFRAG(&Vs[cur][0][0], 16 * ft + l15, 32 * c + 8 * lg);
                o_[0][ft] = __builtin_amdgcn_mfma_f32_16x16x32_f16(pa0[c], vb, o_[0][ft], 0, 0, 0);
                o_[1][ft] = __builtin_amdgcn_mfma_f32_16x16x32_f16(pa1[c], vb, o_[1][ft], 0, 0, 0);
            }
    }

    // ---- epilogue per fragment: rowsum at q=l15; O rows q=4lg+r ----
#pragma unroll
    for (int u = 0; u < 2; ++u) {
        float rs = lp_t[u];
        rs += __shfl_xor(rs, 16);
        rs += __shfl_xor(rs, 32);
        // lanes 0..15 now hold rowsum(q = lane index) for this fragment
#pragma unroll
        for (int r = 0; r < 4; ++r) {
            const float inv = 1.0f / __shfl(rs, 4 * lg + r, 64);
            _Float16* orow = O + (size_t)(b * SEQ + q0 + 16 * (2 * w + u) + 4 * lg + r) * D_MODEL + h * HD + l15;
#pragma unroll
            for (int ft = 0; ft < 4; ++ft) orow[16 * ft] = (_Float16)(o_[u][ft][r] * inv);
        }
    }
}

// ---------------------------------------------------------------------------
extern "C" void kernel_launch(void* const* d_in, const int* in_sizes, int n_in,
                              void* d_out, int out_size, void* d_ws, size_t ws_size,
                              hipStream_t stream)
{
    const float* x  = (const float*)d_in[0];
    const float* wq = (const float*)d_in[1];
    const float* bq = (const float*)d_in[2];
    const float* wk = (const float*)d_in[3];
    const float* bk = (const float*)d_in[4];
    const float* wv = (const float*)d_in[5];
    const float* bv = (const float*)d_in[6];
    const float* wo = (const float*)d_in[7];
    const float* bo = (const float*)d_in[8];
    float* out = (float*)d_out;

    const size_t SZ = (size_t)MTOT * D_MODEL;  // 8388608
    const size_t WZ = (size_t)D_MODEL * D_MODEL;

    _Float16* xh  = (_Float16*)d_ws;
    _Float16* wtq = xh + SZ;
    _Float16* wtk = wtq + WZ;
    _Float16* wtv = wtk + WZ;
    _Float16* wto = wtv + WZ;
    _Float16* Qh  = wto + WZ;
    _Float16* Kh  = Qh + SZ;
    _Float16* Vtg = Kh + SZ;   // V, already transposed [bh][d][s]
    _Float16* AOh = Vtg + SZ;  // total ~88 MiB

    // fused prep: x cvt (blocks 0..255) + 4 weight transposes (256..1279)
    prep<<<dim3(1280), 256, 0, stream>>>(x, xh, wq, wk, wv, wo, wtq, wtk, wtv, wto);
    // QKV projection: XCD-affinity 1D grid (1536 blocks), glds staging
    gemm_mfma<1><<<dim3(1536), 256, 0, stream>>>(xh, wtq, wtk, wtv, bq, bk, bv, Qh, Kh, Vtg);
    // attention: 1024 blocks (16 qt x 64 bh), longest-first, bh-XCD affinity
    attn_fwd_mfma<<<dim3(1024), 256, 0, stream>>>(Qh, Kh, Vtg, AOh);
    // output projection: XCD-affinity 1D grid (512 blocks)
    gemm_mfma<0><<<dim3(512), 256, 0, stream>>>(AOh, wto, wto, wto, bo, bo, bo, out, out, out);
}